// Round 1
// baseline (5677.154 us; speedup 1.0000x reference)
//
#include <hip/hip_runtime.h>

#define T 4096
#define HDIM 64

// ---------------------------------------------------------------------------
// prep: pre0[s][t][i] = b_ih0[i] + b_hh0[i] + sum_d W_ih0[i][d] * in[0,t,d]
// Only batch element 0 of x / y matters (reference uses e[0], o[0] only).
// ---------------------------------------------------------------------------
__global__ void prep_kernel(const float* __restrict__ x, const float* __restrict__ y,
                            const float* __restrict__ eW, const float* __restrict__ ebi,
                            const float* __restrict__ ebh,
                            const float* __restrict__ oW, const float* __restrict__ obi,
                            const float* __restrict__ obh,
                            float* __restrict__ pre)
{
    int idx = blockIdx.x * blockDim.x + threadIdx.x;   // 2*T*64 = 2^19 threads
    int i = idx & 63;
    int t = (idx >> 6) & (T - 1);
    int s = idx >> 18;
    const float* in = s ? y : x;          // batch 0 = first T*3 floats
    const float* W  = s ? oW : eW;        // [64][3]
    const float* bi = s ? obi : ebi;
    const float* bh = s ? obh : ebh;
    float v = bi[i] + bh[i]
            + W[i*3+0]*in[t*3+0] + W[i*3+1]*in[t*3+1] + W[i*3+2]*in[t*3+2];
    pre[idx] = v;
}

// ---------------------------------------------------------------------------
// seq: one block (one wave) per RNN. Lane i owns output row i.
//   h0[t] = tanh(pre[t] + Whh0 @ h0[t-1])
//   h1[t] = tanh(Wih1 @ h0[t] + Whh1 @ h1[t-1] + b_ih1 + b_hh1)
// ---------------------------------------------------------------------------
__global__ __launch_bounds__(64, 1) void seq_kernel(
    const float* __restrict__ pre,            // [2][T][64]
    const float* __restrict__ eWhh0, const float* __restrict__ eWih1,
    const float* __restrict__ eWhh1, const float* __restrict__ ebih1,
    const float* __restrict__ ebhh1,
    const float* __restrict__ oWhh0, const float* __restrict__ oWih1,
    const float* __restrict__ oWhh1, const float* __restrict__ obih1,
    const float* __restrict__ obhh1,
    float* __restrict__ hlast)                // [2][64]
{
    const int s    = blockIdx.x;
    const int lane = threadIdx.x;

    const float* Whh0 = s ? oWhh0 : eWhh0;
    const float* Wih1 = s ? oWih1 : eWih1;
    const float* Whh1 = s ? oWhh1 : eWhh1;
    const float  b1   = s ? (obih1[lane] + obhh1[lane])
                          : (ebih1[lane] + ebhh1[lane]);

    // Row i of each 64x64 weight matrix lives in this lane's registers.
    float w0[64], wi1[64], w1[64];
#pragma unroll
    for (int j = 0; j < 64; ++j) {
        w0[j]  = Whh0[lane * 64 + j];
        wi1[j] = Wih1[lane * 64 + j];
        w1[j]  = Whh1[lane * 64 + j];
    }

    __shared__ __align__(16) float h0s[64];
    __shared__ __align__(16) float h1s[64];
    h0s[lane] = 0.f;
    h1s[lane] = 0.f;
    __syncthreads();

    const float*  p   = pre + s * T * 64;
    const float4* h04 = (const float4*)h0s;
    const float4* h14 = (const float4*)h1s;

    for (int t = 0; t < T; ++t) {
        // --- layer0 matvec (reads h0 old) and layer1-hh matvec (reads h1 old),
        //     interleaved for ILP, 4 partial accumulators each ---
        float a0[4] = { p[t * 64 + lane], 0.f, 0.f, 0.f };
        float a1[4] = { b1, 0.f, 0.f, 0.f };
#pragma unroll
        for (int j4 = 0; j4 < 16; ++j4) {
            float4 v0 = h04[j4];
            float4 v1 = h14[j4];
            a0[0] += w0[j4*4+0] * v0.x;  a0[1] += w0[j4*4+1] * v0.y;
            a0[2] += w0[j4*4+2] * v0.z;  a0[3] += w0[j4*4+3] * v0.w;
            a1[0] += w1[j4*4+0] * v1.x;  a1[1] += w1[j4*4+1] * v1.y;
            a1[2] += w1[j4*4+2] * v1.z;  a1[3] += w1[j4*4+3] * v1.w;
        }
        float h0n = tanhf((a0[0] + a0[1]) + (a0[2] + a0[3]));

        __syncthreads();               // all lanes done reading old h0s/h1s
        h0s[lane] = h0n;
        __syncthreads();               // new h0 visible

        // --- layer1 input matvec (reads h0 new) ---
        float c[4] = { (a1[0] + a1[1]) + (a1[2] + a1[3]), 0.f, 0.f, 0.f };
#pragma unroll
        for (int j4 = 0; j4 < 16; ++j4) {
            float4 v0 = h04[j4];
            c[0] += wi1[j4*4+0] * v0.x;  c[1] += wi1[j4*4+1] * v0.y;
            c[2] += wi1[j4*4+2] * v0.z;  c[3] += wi1[j4*4+3] * v0.w;
        }
        float h1n = tanhf((c[0] + c[1]) + (c[2] + c[3]));

        h1s[lane] = h1n;               // h1s old reads finished before the barriers above
        __syncthreads();               // new h1 visible for next iteration
    }

    hlast[s * 64 + lane] = h1s[lane];
}

// ---------------------------------------------------------------------------
// head: e0 = fce_w@hx + fce_b ; o0 = fco_w@hy + fco_b ; zz=[e0,o0,z];
//       h = relu(fc1_w@zz + fc1_b) ; out = fc2_w@h + fc2_b
// ---------------------------------------------------------------------------
__global__ void head_kernel(const float* __restrict__ hlast,   // [2][64]
                            const float* __restrict__ z,
                            const float* __restrict__ fce_w, const float* __restrict__ fce_b,
                            const float* __restrict__ fco_w, const float* __restrict__ fco_b,
                            const float* __restrict__ fc1_w, const float* __restrict__ fc1_b,
                            const float* __restrict__ fc2_w, const float* __restrict__ fc2_b,
                            float* __restrict__ out)            // [5]
{
    const int lane = threadIdx.x;   // 64 threads
    __shared__ float zz[9];
    __shared__ float hh[64];

    if (lane < 2) {
        float sacc = fce_b[lane];
        for (int j = 0; j < 64; ++j) sacc += fce_w[lane * 64 + j] * hlast[j];
        zz[lane] = sacc;
    } else if (lane < 4) {
        int r = lane - 2;
        float sacc = fco_b[r];
        for (int j = 0; j < 64; ++j) sacc += fco_w[r * 64 + j] * hlast[64 + j];
        zz[lane] = sacc;
    } else if (lane < 9) {
        zz[lane] = z[lane - 4];
    }
    __syncthreads();

    float sacc = fc1_b[lane];
#pragma unroll
    for (int j = 0; j < 9; ++j) sacc += fc1_w[lane * 9 + j] * zz[j];
    hh[lane] = fmaxf(sacc, 0.f);
    __syncthreads();

    if (lane < 5) {
        float o = fc2_b[lane];
        for (int i = 0; i < 64; ++i) o += fc2_w[lane * 64 + i] * hh[i];
        out[lane] = o;
    }
}

// ---------------------------------------------------------------------------
extern "C" void kernel_launch(void* const* d_in, const int* in_sizes, int n_in,
                              void* d_out, int out_size, void* d_ws, size_t ws_size,
                              hipStream_t stream)
{
    const float* x      = (const float*)d_in[0];
    const float* y      = (const float*)d_in[1];
    const float* z      = (const float*)d_in[2];
    const float* e_Wih0 = (const float*)d_in[3];
    const float* e_Whh0 = (const float*)d_in[4];
    const float* e_bih0 = (const float*)d_in[5];
    const float* e_bhh0 = (const float*)d_in[6];
    const float* e_Wih1 = (const float*)d_in[7];
    const float* e_Whh1 = (const float*)d_in[8];
    const float* e_bih1 = (const float*)d_in[9];
    const float* e_bhh1 = (const float*)d_in[10];
    const float* o_Wih0 = (const float*)d_in[11];
    const float* o_Whh0 = (const float*)d_in[12];
    const float* o_bih0 = (const float*)d_in[13];
    const float* o_bhh0 = (const float*)d_in[14];
    const float* o_Wih1 = (const float*)d_in[15];
    const float* o_Whh1 = (const float*)d_in[16];
    const float* o_bih1 = (const float*)d_in[17];
    const float* o_bhh1 = (const float*)d_in[18];
    const float* fce_w  = (const float*)d_in[19];
    const float* fce_b  = (const float*)d_in[20];
    const float* fco_w  = (const float*)d_in[21];
    const float* fco_b  = (const float*)d_in[22];
    const float* fc1_w  = (const float*)d_in[23];
    const float* fc1_b  = (const float*)d_in[24];
    const float* fc2_w  = (const float*)d_in[25];
    const float* fc2_b  = (const float*)d_in[26];

    float* pre   = (float*)d_ws;            // 2*T*64 floats = 2 MB
    float* hlast = pre + 2 * T * 64;        // 128 floats
    float* out   = (float*)d_out;

    prep_kernel<<<(2 * T * 64) / 256, 256, 0, stream>>>(
        x, y, e_Wih0, e_bih0, e_bhh0, o_Wih0, o_bih0, o_bhh0, pre);

    seq_kernel<<<2, 64, 0, stream>>>(
        pre,
        e_Whh0, e_Wih1, e_Whh1, e_bih1, e_bhh1,
        o_Whh0, o_Wih1, o_Whh1, o_bih1, o_bhh1,
        hlast);

    head_kernel<<<1, 64, 0, stream>>>(
        hlast, z, fce_w, fce_b, fco_w, fco_b, fc1_w, fc1_b, fc2_w, fc2_b, out);
}

// Round 4
// 2413.554 us; speedup vs baseline: 2.3522x; 2.3522x over previous
//
#include <hip/hip_runtime.h>

#define T 4096

// ---------------------------------------------------------------------------
// prep: pre[s][t][i] = b_ih0[i] + b_hh0[i] + sum_d W_ih0[i][d] * in[0,t,d]
// Only batch element 0 of x / y matters (reference uses e[0], o[0] only).
// ---------------------------------------------------------------------------
__global__ void prep_kernel(const float* __restrict__ x, const float* __restrict__ y,
                            const float* __restrict__ eW, const float* __restrict__ ebi,
                            const float* __restrict__ ebh,
                            const float* __restrict__ oW, const float* __restrict__ obi,
                            const float* __restrict__ obh,
                            float* __restrict__ pre)
{
    int idx = blockIdx.x * blockDim.x + threadIdx.x;   // 2*T*64 threads
    int i = idx & 63;
    int t = (idx >> 6) & (T - 1);
    int s = idx >> 18;
    const float* in = s ? y : x;          // batch 0 = first T*3 floats
    const float* W  = s ? oW : eW;        // [64][3]
    const float* bi = s ? obi : ebi;
    const float* bh = s ? obh : ebh;
    float v = bi[i] + bh[i]
            + W[i*3+0]*in[t*3+0] + W[i*3+1]*in[t*3+1] + W[i*3+2]*in[t*3+2];
    pre[idx] = v;
}

// ---------------------------------------------------------------------------
// seq: one block of 2 waves per RNN, 1 barrier per pipeline slot.
//   wave0 @ slot t:  h0[t]   = tanh(p[t] + Whh0@h0[t-1])            (t < T)
//                    qp0[t-1]= b1 + Wih1[:,0:32]@h0[t-1][0:32]      (t <= T !!)
//   wave1 @ slot t:  qp1[t-1]= Wih1[:,32:]@h0[t-1][32:]             (1 <= t <= T)
//                    h1[t-2] = tanh(qp0[t-2] + qp1[t-2] + Whh1@h1[t-3])  (t >= 2)
// Double-buffered h0/h1/qp0 in LDS; h0[-1]=h1[-1]=0.
// BUGFIX (R3->R4): qp0[t-1] must run through t==T, else qp0[T-1] is never
// written and h1[T-1] reads stale qp0[T-3] (deterministic absmax 8.8e-3).
// ---------------------------------------------------------------------------
__global__ __launch_bounds__(128, 1) void seq_kernel(
    const float* __restrict__ pre,            // [2][T][64]
    const float* __restrict__ eWhh0, const float* __restrict__ eWih1,
    const float* __restrict__ eWhh1, const float* __restrict__ ebih1,
    const float* __restrict__ ebhh1,
    const float* __restrict__ oWhh0, const float* __restrict__ oWih1,
    const float* __restrict__ oWhh1, const float* __restrict__ obih1,
    const float* __restrict__ obhh1,
    float* __restrict__ hlast)                // [2][64]
{
    const int s    = blockIdx.x;
    const int wv   = threadIdx.x >> 6;
    const int lane = threadIdx.x & 63;

    __shared__ __align__(16) float h0buf[2][64];
    __shared__ __align__(16) float h1buf[2][64];
    __shared__ __align__(16) float qbuf[2][64];

    const float* Whh0 = s ? oWhh0 : eWhh0;
    const float* Wih1 = s ? oWih1 : eWih1;
    const float* Whh1 = s ? oWhh1 : eWhh1;
    const float  b1   = s ? (obih1[lane] + obhh1[lane])
                          : (ebih1[lane] + ebhh1[lane]);
    const float* p    = pre + s * T * 64;

    if (wv == 0) { h0buf[1][lane] = 0.f; h1buf[1][lane] = 0.f; }
    __syncthreads();

    if (wv == 0) {
        // -------- layer-0 wave --------
        float w0[64], wlo[32];
#pragma unroll
        for (int j = 0; j < 64; ++j) w0[j]  = Whh0[lane * 64 + j];
#pragma unroll
        for (int j = 0; j < 32; ++j) wlo[j] = Wih1[lane * 64 + j];

        float p_cur = p[lane];
        for (int t = 0; t <= T + 1; ++t) {
            if (t <= T) {
                float p_nxt = (t + 1 < T) ? p[(t + 1) * 64 + lane] : 0.f;  // prefetch
                const float4* hv = (const float4*)h0buf[(t - 1) & 1];
                float a0 = p_cur, a1 = 0.f, a2 = 0.f, a3 = 0.f;
                float q0 = b1,    q1 = 0.f, q2 = 0.f, q3 = 0.f;
#pragma unroll
                for (int j4 = 0; j4 < 8; ++j4) {
                    float4 v = hv[j4];
                    a0 = fmaf(w0[4*j4+0], v.x, a0);  a1 = fmaf(w0[4*j4+1], v.y, a1);
                    a2 = fmaf(w0[4*j4+2], v.z, a2);  a3 = fmaf(w0[4*j4+3], v.w, a3);
                    q0 = fmaf(wlo[4*j4+0], v.x, q0); q1 = fmaf(wlo[4*j4+1], v.y, q1);
                    q2 = fmaf(wlo[4*j4+2], v.z, q2); q3 = fmaf(wlo[4*j4+3], v.w, q3);
                }
#pragma unroll
                for (int j4 = 8; j4 < 16; ++j4) {
                    float4 v = hv[j4];
                    a0 = fmaf(w0[4*j4+0], v.x, a0);  a1 = fmaf(w0[4*j4+1], v.y, a1);
                    a2 = fmaf(w0[4*j4+2], v.z, a2);  a3 = fmaf(w0[4*j4+3], v.w, a3);
                }
                if (t < T) {
                    float h0n = tanhf((a0 + a1) + (a2 + a3));
                    h0buf[t & 1][lane] = h0n;
                }
                qbuf[(t - 1) & 1][lane] = (q0 + q1) + (q2 + q3);
                p_cur = p_nxt;
            }
            __syncthreads();
        }
    } else {
        // -------- layer-1 wave --------
        float whi[32], w1[64];
#pragma unroll
        for (int j = 0; j < 32; ++j) whi[j] = Wih1[lane * 64 + 32 + j];
#pragma unroll
        for (int j = 0; j < 64; ++j) w1[j]  = Whh1[lane * 64 + j];

        float qp1_cur = 0.f;   // qp1 for step (slot-1), set at end of each slot
        float h1_last = 0.f;
        for (int t = 0; t <= T + 1; ++t) {
            float nq = 0.f;
            if (t >= 1 && t <= T) {          // qp1[t-1] = Wih1[:,32:]@h0[t-1][32:]
                const float4* hv = ((const float4*)h0buf[(t - 1) & 1]) + 8;
                float q0 = 0.f, q1 = 0.f, q2 = 0.f, q3 = 0.f;
#pragma unroll
                for (int j4 = 0; j4 < 8; ++j4) {
                    float4 v = hv[j4];
                    q0 = fmaf(whi[4*j4+0], v.x, q0); q1 = fmaf(whi[4*j4+1], v.y, q1);
                    q2 = fmaf(whi[4*j4+2], v.z, q2); q3 = fmaf(whi[4*j4+3], v.w, q3);
                }
                nq = (q0 + q1) + (q2 + q3);
            }
            if (t >= 2) {                    // h1[t-2]
                const float4* h1v = (const float4*)h1buf[(t - 1) & 1];  // h1[t-3]
                float c0 = qbuf[(t - 2) & 1][lane] + qp1_cur;           // qp0+qp1 for t-2
                float c1 = 0.f, c2 = 0.f, c3 = 0.f;
#pragma unroll
                for (int j4 = 0; j4 < 16; ++j4) {
                    float4 v = h1v[j4];
                    c0 = fmaf(w1[4*j4+0], v.x, c0);  c1 = fmaf(w1[4*j4+1], v.y, c1);
                    c2 = fmaf(w1[4*j4+2], v.z, c2);  c3 = fmaf(w1[4*j4+3], v.w, c3);
                }
                float h1n = tanhf((c0 + c1) + (c2 + c3));
                h1buf[t & 1][lane] = h1n;    // (t-2)&1 == t&1
                h1_last = h1n;
            }
            qp1_cur = nq;
            __syncthreads();
        }
        hlast[s * 64 + lane] = h1_last;
    }
}

// ---------------------------------------------------------------------------
// head: e0 = fce_w@hx + fce_b ; o0 = fco_w@hy + fco_b ; zz=[e0,o0,z];
//       h = relu(fc1_w@zz + fc1_b) ; out = fc2_w@h + fc2_b
// ---------------------------------------------------------------------------
__global__ void head_kernel(const float* __restrict__ hlast,   // [2][64]
                            const float* __restrict__ z,
                            const float* __restrict__ fce_w, const float* __restrict__ fce_b,
                            const float* __restrict__ fco_w, const float* __restrict__ fco_b,
                            const float* __restrict__ fc1_w, const float* __restrict__ fc1_b,
                            const float* __restrict__ fc2_w, const float* __restrict__ fc2_b,
                            float* __restrict__ out)            // [5]
{
    const int lane = threadIdx.x;   // 64 threads
    __shared__ float zz[9];
    __shared__ float hh[64];

    if (lane < 2) {
        float sacc = fce_b[lane];
        for (int j = 0; j < 64; ++j) sacc += fce_w[lane * 64 + j] * hlast[j];
        zz[lane] = sacc;
    } else if (lane < 4) {
        int r = lane - 2;
        float sacc = fco_b[r];
        for (int j = 0; j < 64; ++j) sacc += fco_w[r * 64 + j] * hlast[64 + j];
        zz[lane] = sacc;
    } else if (lane < 9) {
        zz[lane] = z[lane - 4];
    }
    __syncthreads();

    float sacc = fc1_b[lane];
#pragma unroll
    for (int j = 0; j < 9; ++j) sacc += fc1_w[lane * 9 + j] * zz[j];
    hh[lane] = fmaxf(sacc, 0.f);
    __syncthreads();

    if (lane < 5) {
        float o = fc2_b[lane];
        for (int i = 0; i < 64; ++i) o += fc2_w[lane * 64 + i] * hh[i];
        out[lane] = o;
    }
}

// ---------------------------------------------------------------------------
extern "C" void kernel_launch(void* const* d_in, const int* in_sizes, int n_in,
                              void* d_out, int out_size, void* d_ws, size_t ws_size,
                              hipStream_t stream)
{
    const float* x      = (const float*)d_in[0];
    const float* y      = (const float*)d_in[1];
    const float* z      = (const float*)d_in[2];
    const float* e_Wih0 = (const float*)d_in[3];
    const float* e_Whh0 = (const float*)d_in[4];
    const float* e_bih0 = (const float*)d_in[5];
    const float* e_bhh0 = (const float*)d_in[6];
    const float* e_Wih1 = (const float*)d_in[7];
    const float* e_Whh1 = (const float*)d_in[8];
    const float* e_bih1 = (const float*)d_in[9];
    const float* e_bhh1 = (const float*)d_in[10];
    const float* o_Wih0 = (const float*)d_in[11];
    const float* o_Whh0 = (const float*)d_in[12];
    const float* o_bih0 = (const float*)d_in[13];
    const float* o_bhh0 = (const float*)d_in[14];
    const float* o_Wih1 = (const float*)d_in[15];
    const float* o_Whh1 = (const float*)d_in[16];
    const float* o_bih1 = (const float*)d_in[17];
    const float* o_bhh1 = (const float*)d_in[18];
    const float* fce_w  = (const float*)d_in[19];
    const float* fce_b  = (const float*)d_in[20];
    const float* fco_w  = (const float*)d_in[21];
    const float* fco_b  = (const float*)d_in[22];
    const float* fc1_w  = (const float*)d_in[23];
    const float* fc1_b  = (const float*)d_in[24];
    const float* fc2_w  = (const float*)d_in[25];
    const float* fc2_b  = (const float*)d_in[26];

    float* pre   = (float*)d_ws;            // 2*T*64 floats = 2 MB
    float* hlast = pre + 2 * T * 64;        // 128 floats
    float* out   = (float*)d_out;

    prep_kernel<<<(2 * T * 64) / 256, 256, 0, stream>>>(
        x, y, e_Wih0, e_bih0, e_bhh0, o_Wih0, o_bih0, o_bhh0, pre);

    seq_kernel<<<2, 128, 0, stream>>>(
        pre,
        e_Whh0, e_Wih1, e_Whh1, e_bih1, e_bhh1,
        o_Whh0, o_Wih1, o_Whh1, o_bih1, o_bhh1,
        hlast);

    head_kernel<<<1, 64, 0, stream>>>(
        hlast, z, fce_w, fce_b, fco_w, fco_b, fc1_w, fc1_b, fc2_w, fc2_b, out);
}